// Round 5
// baseline (1740.701 us; speedup 1.0000x reference)
//
#include <hip/hip_runtime.h>

// RNN_SingleOutput: 2-layer Elman ReLU RNN, B=256 T=512 I=64 H=256, fp32.
// Round-5:
//  * Round-4 diagnosis: 512-thr blocks need 128 weight-floats/thread; the
//    allocator parked them in AGPRs (VGPR_Count=84, no spill traffic) and the
//    accvgpr round-trips doubled VALU work (49%busy x 2677cy/step vs 640 floor).
//  * Fix: 1024-thr blocks -> 64 weight-floats/thread (16 float4), total live
//    ~110 <= the 128-reg cap of 4 waves/SIMD. No pins. 2x waves to hide
//    ds_read/shfl/barrier latency.
//  * Layout: s=tid&15 (K-slice of 16 cols = 4 f4), g=tid>>4 (output quad
//    4g..4g+3). Split-K reduced by 4-stage shfl_xor butterfly (1,2,4,8).
//  * LDS h broadcast: padded element e at e+(e>>3); worst case 2-way
//    conflict = free. All register arrays statically indexed (rule #20).
// ws requirement: B*T*H*4 = 128 MiB.

#define B_ 256
#define T_ 512
#define I_ 64
#define H_ 256

__device__ __forceinline__ float red16(float a) {  // sum over lane bits 0..3
    a += __shfl_xor(a, 1, 64);
    a += __shfl_xor(a, 2, 64);
    a += __shfl_xor(a, 4, 64);
    a += __shfl_xor(a, 8, 64);
    return a;
}

#define FMA4(acc, hv, wv)                      \
    do {                                       \
        acc = fmaf((hv).x, (wv).x, acc);       \
        acc = fmaf((hv).y, (wv).y, acc);       \
        acc = fmaf((hv).z, (wv).z, acc);       \
        acc = fmaf((hv).w, (wv).w, acc);       \
    } while (0)

// ---------------------------------------------------------------- layer 0 ---
__global__ __launch_bounds__(1024) void k_layer0(
    const float* __restrict__ x, const float* __restrict__ Wih,
    const float* __restrict__ Whh, const float* __restrict__ bih,
    const float* __restrict__ bhh, float* __restrict__ h1out)
{
    const int tid = threadIdx.x;
    const int s = tid & 15;       // k-slice: h cols 16s..16s+15, x cols 4s..4s+3
    const int g = tid >> 4;       // output quad 4g..4g+3
    const int b = blockIdx.x;

    float4 whh[4][4], wih[4];
#pragma unroll
    for (int r = 0; r < 4; ++r) {
        const float4* pw = (const float4*)(Whh + (size_t)(4 * g + r) * H_ + 16 * s);
#pragma unroll
        for (int i = 0; i < 4; ++i) whh[r][i] = pw[i];
        wih[r] = *(const float4*)(Wih + (size_t)(4 * g + r) * I_ + 4 * s);
    }
    float4 bias4;
    {
        float4 b1 = ((const float4*)bih)[g], b2 = ((const float4*)bhh)[g];
        bias4 = make_float4(b1.x + b2.x, b1.y + b2.y, b1.z + b2.z, b1.w + b2.w);
    }

    __shared__ float4 hbuf[2][72];          // padded: element e at e+(e>>3)
    __shared__ float4 xs[(32 * I_) / 4];    // 32-step x chunk, 8 KB

    if (tid < 64) hbuf[0][tid + (tid >> 3)] = make_float4(0.f, 0.f, 0.f, 0.f);
    const int wloc = g + (g >> 3);          // padded store slot for quad g

    int p = 0;
#pragma unroll 1
    for (int t0 = 0; t0 < T_; t0 += 32) {
        if (tid < 512)
            xs[tid] = ((const float4*)(x + ((size_t)b * T_ + t0) * I_))[tid];
        __syncthreads();
#pragma unroll 1
        for (int tt = 0; tt < 32; ++tt) {
            float4 hv[4];
            {
                const int e0 = 4 * s;       // f4 elements e0..e0+3, padded
#pragma unroll
                for (int i = 0; i < 4; ++i) {
                    const int e = e0 + i;
                    hv[i] = hbuf[p][e + (e >> 3)];
                }
            }
            const float4 xv = xs[tt * (I_ / 4) + s];
            float a[4] = {0.f, 0.f, 0.f, 0.f};
#pragma unroll
            for (int r = 0; r < 4; ++r) {
#pragma unroll
                for (int i = 0; i < 4; ++i) FMA4(a[r], hv[i], whh[r][i]);
                FMA4(a[r], xv, wih[r]);
            }
#pragma unroll
            for (int r = 0; r < 4; ++r) a[r] = red16(a[r]);
            float4 v;
            v.x = fmaxf(a[0] + bias4.x, 0.f);
            v.y = fmaxf(a[1] + bias4.y, 0.f);
            v.z = fmaxf(a[2] + bias4.z, 0.f);
            v.w = fmaxf(a[3] + bias4.w, 0.f);
            if (s == 0) {
                hbuf[p ^ 1][wloc] = v;
                ((float4*)(h1out + ((size_t)b * T_ + t0 + tt) * H_))[g] = v;
            }
            __syncthreads();
            p ^= 1;
        }
    }
}

// ------------------------------------------------------------- inproj L1 ---
// pre1 = h1 @ W_ih1^T + (b_ih1 + b_hh1), in place over `buf`.
__global__ __launch_bounds__(1024) void k_inproj1(
    float* __restrict__ buf, const float* __restrict__ Wih,
    const float* __restrict__ bih, const float* __restrict__ bhh)
{
    const int tid = threadIdx.x;
    const int s = tid & 15, g = tid >> 4;

    float4 w[4][4];
#pragma unroll
    for (int r = 0; r < 4; ++r) {
        const float4* pw = (const float4*)(Wih + (size_t)(4 * g + r) * H_ + 16 * s);
#pragma unroll
        for (int i = 0; i < 4; ++i) w[r][i] = pw[i];
    }
    float4 bias4;
    {
        float4 b1 = ((const float4*)bih)[g], b2 = ((const float4*)bhh)[g];
        bias4 = make_float4(b1.x + b2.x, b1.y + b2.y, b1.z + b2.z, b1.w + b2.w);
    }

    __shared__ float4 rows4[16 * 72];   // 16 rows, padded, 18 KB

    const size_t m0 = (size_t)blockIdx.x * 64;
#pragma unroll 1
    for (int c = 0; c < 4; ++c) {
        float* rowbase = buf + (m0 + 16 * c) * H_;
        {
            const int r = tid >> 6, e = tid & 63;
            rows4[r * 72 + e + (e >> 3)] = ((const float4*)rowbase)[tid];
        }
        __syncthreads();
#pragma unroll 1
        for (int r = 0; r < 16; ++r) {
            float4 hv[4];
#pragma unroll
            for (int i = 0; i < 4; ++i) {
                const int e = 4 * s + i;
                hv[i] = rows4[r * 72 + e + (e >> 3)];
            }
            float a[4] = {0.f, 0.f, 0.f, 0.f};
#pragma unroll
            for (int q = 0; q < 4; ++q)
#pragma unroll
                for (int i = 0; i < 4; ++i) FMA4(a[q], hv[i], w[q][i]);
#pragma unroll
            for (int q = 0; q < 4; ++q) a[q] = red16(a[q]);
            if (s == 0) {
                float4 v = make_float4(a[0] + bias4.x, a[1] + bias4.y,
                                       a[2] + bias4.z, a[3] + bias4.w);
                ((float4*)rowbase)[r * (H_ / 4) + g] = v;   // LDS copy is source
            }
        }
        __syncthreads();   // all LDS reads done before next chunk restage
    }
}

// ---------------------------------------------------------------- layer 1 ---
__global__ __launch_bounds__(1024) void k_layer1(
    const float* __restrict__ pre1, const float* __restrict__ Whh,
    const float* __restrict__ Wfc, const float* __restrict__ bfcp,
    float* __restrict__ out)
{
    const int tid = threadIdx.x;
    const int s = tid & 15, g = tid >> 4;
    const int b = blockIdx.x;

    float4 whh[4][4];
#pragma unroll
    for (int r = 0; r < 4; ++r) {
        const float4* pw = (const float4*)(Whh + (size_t)(4 * g + r) * H_ + 16 * s);
#pragma unroll
        for (int i = 0; i < 4; ++i) whh[r][i] = pw[i];
    }
    const float4 wfc4 = ((const float4*)Wfc)[g];
    const float  bfc  = bfcp[0];

    __shared__ float4 hbuf[2][72];            // padded
    __shared__ float4 pchunk[(16 * H_) / 4];  // 16-step pre1 chunk, 16 KB
    __shared__ float  wavesum[2][16];

    if (tid < 64) hbuf[0][tid + (tid >> 3)] = make_float4(0.f, 0.f, 0.f, 0.f);
    const int wloc = g + (g >> 3);

    int p = 0;
#pragma unroll 1
    for (int t0 = 0; t0 < T_; t0 += 16) {
        pchunk[tid] = ((const float4*)(pre1 + ((size_t)b * T_ + t0) * H_))[tid];
        __syncthreads();
#pragma unroll 1
        for (int tt = 0; tt < 16; ++tt) {
            const int t = t0 + tt;
            if (tid == 0 && t > 0) {          // deferred FC store for step t-1
                float sfc = bfc;
#pragma unroll
                for (int wv = 0; wv < 16; ++wv) sfc += wavesum[p ^ 1][wv];
                out[(size_t)b * T_ + (t - 1)] = sfc;
            }
            float4 hv[4];
#pragma unroll
            for (int i = 0; i < 4; ++i) {
                const int e = 4 * s + i;
                hv[i] = hbuf[p][e + (e >> 3)];
            }
            float a[4] = {0.f, 0.f, 0.f, 0.f};
#pragma unroll
            for (int r = 0; r < 4; ++r)
#pragma unroll
                for (int i = 0; i < 4; ++i) FMA4(a[r], hv[i], whh[r][i]);
#pragma unroll
            for (int r = 0; r < 4; ++r) a[r] = red16(a[r]);
            const float4 pre = pchunk[tt * (H_ / 4) + g];
            float4 v;
            v.x = fmaxf(a[0] + pre.x, 0.f);
            v.y = fmaxf(a[1] + pre.y, 0.f);
            v.z = fmaxf(a[2] + pre.z, 0.f);
            v.w = fmaxf(a[3] + pre.w, 0.f);
            float fc = v.x * wfc4.x;
            fc = fmaf(v.y, wfc4.y, fc);
            fc = fmaf(v.z, wfc4.z, fc);
            fc = fmaf(v.w, wfc4.w, fc);
            fc += __shfl_xor(fc, 16, 64);     // sum over the wave's 4 quads
            fc += __shfl_xor(fc, 32, 64);
            if (s == 0) hbuf[p ^ 1][wloc] = v;
            if ((tid & 63) == 0) wavesum[p][tid >> 6] = fc;
            __syncthreads();
            p ^= 1;
        }
    }
    if (tid == 0) {                            // final step's FC store
        float sfc = bfc;
#pragma unroll
        for (int wv = 0; wv < 16; ++wv) sfc += wavesum[p ^ 1][wv];
        out[(size_t)b * T_ + (T_ - 1)] = sfc;
    }
}

extern "C" void kernel_launch(void* const* d_in, const int* in_sizes, int n_in,
                              void* d_out, int out_size, void* d_ws, size_t ws_size,
                              hipStream_t stream) {
    (void)in_sizes; (void)n_in; (void)out_size; (void)ws_size;
    const float* x    = (const float*)d_in[0];
    const float* Wih0 = (const float*)d_in[1];
    const float* Whh0 = (const float*)d_in[2];
    const float* bih0 = (const float*)d_in[3];
    const float* bhh0 = (const float*)d_in[4];
    const float* Wih1 = (const float*)d_in[5];
    const float* Whh1 = (const float*)d_in[6];
    const float* bih1 = (const float*)d_in[7];
    const float* bhh1 = (const float*)d_in[8];
    const float* Wfc  = (const float*)d_in[9];
    const float* bfc  = (const float*)d_in[10];

    float* buf = (float*)d_ws;      // B*T*H*4 = 128 MiB scratch
    float* out = (float*)d_out;

    k_layer0 <<<dim3(B_),             dim3(1024), 0, stream>>>(x, Wih0, Whh0, bih0, bhh0, buf);
    k_inproj1<<<dim3((B_ * T_) / 64), dim3(1024), 0, stream>>>(buf, Wih1, bih1, bhh1);
    k_layer1 <<<dim3(B_),             dim3(1024), 0, stream>>>(buf, Whh1, Wfc, bfc, out);
}

// Round 6
// 1247.886 us; speedup vs baseline: 1.3949x; 1.3949x over previous
//
#include <hip/hip_runtime.h>

// RNN_SingleOutput: 2-layer Elman ReLU RNN, B=256 T=512 I=64 H=256, fp32.
// Round-6: round-4 code + __attribute__((amdgpu_waves_per_eu(2,2))).
//  History of the one core problem (weights must be VGPR-resident):
//   R1/R2: (512,2) -> cap 128 < 160 needed -> remat-reload from L2. 705us.
//   R3: runtime-indexed reg array -> scratch (rule #20). 29ms.
//   R4: pins stop remat, but scheduler's occupancy target spills the pinned
//       values to AGPRs instead (VGPR=84, accvgpr round-trips 2x VALU). 571us.
//   R5: 1024thr/64 floats: scheduler targeted ~8 waves/EU (VGPR=52) and
//       remat-reloaded W every step -> L2-BW-bound 3365 cy/step. 718us.
//  Fix: amdgpu_waves_per_eu(2,2) sets the scheduler's occupancy target to
//  exactly 2 waves/EU (cap 256 arch VGPRs) -> no motive to remat or spill.
// ws requirement: B*T*H*4 = 128 MiB.

#define B_ 256
#define T_ 512
#define I_ 64
#define H_ 256

#define PIN4(v) asm volatile("" : "+v"((v).x), "+v"((v).y), "+v"((v).z), "+v"((v).w))

__device__ __forceinline__ float red8(float a) {   // sum over s = lane bits 0..2
    a += __shfl_xor(a, 1, 64);
    a += __shfl_xor(a, 2, 64);
    a += __shfl_xor(a, 4, 64);
    return a;
}

// ---------------------------------------------------------------- layer 0 ---
__attribute__((amdgpu_waves_per_eu(2, 2)))
__global__ __launch_bounds__(512) void k_layer0(
    const float* __restrict__ x, const float* __restrict__ Wih,
    const float* __restrict__ Whh, const float* __restrict__ bih,
    const float* __restrict__ bhh, float* __restrict__ h1out)
{
    const int tid = threadIdx.x;
    const int s = tid & 7;        // k-slice: h cols 32s..32s+31, x cols 8s..8s+7
    const int g = tid >> 3;       // output quad 4g..4g+3
    const int b = blockIdx.x;

    float4 whh[4][8], wih[4][2];
#pragma unroll
    for (int r = 0; r < 4; ++r) {
        const float4* pw = (const float4*)(Whh + (size_t)(4 * g + r) * H_ + 32 * s);
#pragma unroll
        for (int i = 0; i < 8; ++i) whh[r][i] = pw[i];
        const float4* px = (const float4*)(Wih + (size_t)(4 * g + r) * I_ + 8 * s);
        wih[r][0] = px[0]; wih[r][1] = px[1];
    }
#pragma unroll
    for (int r = 0; r < 4; ++r) {
#pragma unroll
        for (int i = 0; i < 8; ++i) PIN4(whh[r][i]);
        PIN4(wih[r][0]); PIN4(wih[r][1]);
    }
    float4 bias4;
    {
        float4 b1 = ((const float4*)bih)[g], b2 = ((const float4*)bhh)[g];
        bias4 = make_float4(b1.x + b2.x, b1.y + b2.y, b1.z + b2.z, b1.w + b2.w);
    }

    __shared__ float4 hbuf[2][72];          // padded: element e at e+(e>>3)
    __shared__ float4 xs[(32 * I_) / 4];    // 32-step x chunk, 8 KB

    if (tid < 64) hbuf[0][tid + (tid >> 3)] = make_float4(0.f, 0.f, 0.f, 0.f);
    const int wloc = g + (g >> 3);          // padded store slot for quad g

    int p = 0;
#pragma unroll 1
    for (int t0 = 0; t0 < T_; t0 += 32) {
        xs[tid] = ((const float4*)(x + ((size_t)b * T_ + t0) * I_))[tid];
        __syncthreads();
#pragma unroll 1
        for (int tt = 0; tt < 32; ++tt) {
            float4 hv[8];
            const float4* hp = &hbuf[p][9 * s];
#pragma unroll
            for (int i = 0; i < 8; ++i) hv[i] = hp[i];
            float4 xv0, xv1;
            {
                const float4* xp = xs + tt * (I_ / 4) + 2 * s;
                xv0 = xp[0]; xv1 = xp[1];
            }
            float a[4] = {0.f, 0.f, 0.f, 0.f};
#pragma unroll
            for (int r = 0; r < 4; ++r) {
#pragma unroll
                for (int i = 0; i < 8; ++i) {
                    a[r] = fmaf(hv[i].x, whh[r][i].x, a[r]);
                    a[r] = fmaf(hv[i].y, whh[r][i].y, a[r]);
                    a[r] = fmaf(hv[i].z, whh[r][i].z, a[r]);
                    a[r] = fmaf(hv[i].w, whh[r][i].w, a[r]);
                }
                a[r] = fmaf(xv0.x, wih[r][0].x, a[r]);
                a[r] = fmaf(xv0.y, wih[r][0].y, a[r]);
                a[r] = fmaf(xv0.z, wih[r][0].z, a[r]);
                a[r] = fmaf(xv0.w, wih[r][0].w, a[r]);
                a[r] = fmaf(xv1.x, wih[r][1].x, a[r]);
                a[r] = fmaf(xv1.y, wih[r][1].y, a[r]);
                a[r] = fmaf(xv1.z, wih[r][1].z, a[r]);
                a[r] = fmaf(xv1.w, wih[r][1].w, a[r]);
            }
#pragma unroll
            for (int r = 0; r < 4; ++r) a[r] = red8(a[r]);
            float4 v;
            v.x = fmaxf(a[0] + bias4.x, 0.f);
            v.y = fmaxf(a[1] + bias4.y, 0.f);
            v.z = fmaxf(a[2] + bias4.z, 0.f);
            v.w = fmaxf(a[3] + bias4.w, 0.f);
            if (s == 0) {
                hbuf[p ^ 1][wloc] = v;
                ((float4*)(h1out + ((size_t)b * T_ + t0 + tt) * H_))[g] = v;
            }
            __syncthreads();
            p ^= 1;
        }
    }
}

// ------------------------------------------------------------- inproj L1 ---
// pre1 = h1 @ W_ih1^T + (b_ih1 + b_hh1), in place over `buf`.
__attribute__((amdgpu_waves_per_eu(2, 2)))
__global__ __launch_bounds__(512) void k_inproj1(
    float* __restrict__ buf, const float* __restrict__ Wih,
    const float* __restrict__ bih, const float* __restrict__ bhh)
{
    const int tid = threadIdx.x;
    const int s = tid & 7, g = tid >> 3;

    float4 w[4][8];
#pragma unroll
    for (int r = 0; r < 4; ++r) {
        const float4* pw = (const float4*)(Wih + (size_t)(4 * g + r) * H_ + 32 * s);
#pragma unroll
        for (int i = 0; i < 8; ++i) w[r][i] = pw[i];
    }
#pragma unroll
    for (int r = 0; r < 4; ++r)
#pragma unroll
        for (int i = 0; i < 8; ++i) PIN4(w[r][i]);
    float4 bias4;
    {
        float4 b1 = ((const float4*)bih)[g], b2 = ((const float4*)bhh)[g];
        bias4 = make_float4(b1.x + b2.x, b1.y + b2.y, b1.z + b2.z, b1.w + b2.w);
    }

    __shared__ float4 rows4[16 * 72];   // 16 rows, padded stride 9/slice, 18 KB

    const size_t m0 = (size_t)blockIdx.x * 64;
#pragma unroll 1
    for (int c = 0; c < 4; ++c) {
        float* rowbase = buf + (m0 + 16 * c) * H_;
#pragma unroll
        for (int k = 0; k < 4; ++k) {
            const int flat = tid + 512 * k;
            const int r = flat >> 6, e = flat & 63;
            rows4[r * 72 + e + (e >> 3)] = ((const float4*)rowbase)[flat];
        }
        __syncthreads();
#pragma unroll 1
        for (int r = 0; r < 16; ++r) {
            float4 hv[8];
            const float4* hp = &rows4[r * 72 + 9 * s];
#pragma unroll
            for (int i = 0; i < 8; ++i) hv[i] = hp[i];
            float a[4] = {0.f, 0.f, 0.f, 0.f};
#pragma unroll
            for (int q = 0; q < 4; ++q)
#pragma unroll
                for (int i = 0; i < 8; ++i) {
                    a[q] = fmaf(hv[i].x, w[q][i].x, a[q]);
                    a[q] = fmaf(hv[i].y, w[q][i].y, a[q]);
                    a[q] = fmaf(hv[i].z, w[q][i].z, a[q]);
                    a[q] = fmaf(hv[i].w, w[q][i].w, a[q]);
                }
#pragma unroll
            for (int q = 0; q < 4; ++q) a[q] = red8(a[q]);
            if (s == 0) {
                float4 v = make_float4(a[0] + bias4.x, a[1] + bias4.y,
                                       a[2] + bias4.z, a[3] + bias4.w);
                ((float4*)rowbase)[r * (H_ / 4) + g] = v;   // LDS copy is source
            }
        }
        __syncthreads();   // all LDS reads done before next chunk restage
    }
}

// ---------------------------------------------------------------- layer 1 ---
__attribute__((amdgpu_waves_per_eu(2, 2)))
__global__ __launch_bounds__(512) void k_layer1(
    const float* __restrict__ pre1, const float* __restrict__ Whh,
    const float* __restrict__ Wfc, const float* __restrict__ bfcp,
    float* __restrict__ out)
{
    const int tid = threadIdx.x;
    const int s = tid & 7, g = tid >> 3;
    const int b = blockIdx.x;

    float4 whh[4][8];
#pragma unroll
    for (int r = 0; r < 4; ++r) {
        const float4* pw = (const float4*)(Whh + (size_t)(4 * g + r) * H_ + 32 * s);
#pragma unroll
        for (int i = 0; i < 8; ++i) whh[r][i] = pw[i];
    }
#pragma unroll
    for (int r = 0; r < 4; ++r)
#pragma unroll
        for (int i = 0; i < 8; ++i) PIN4(whh[r][i]);
    const float4 wfc4 = ((const float4*)Wfc)[g];
    const float  bfc  = bfcp[0];

    __shared__ float4 hbuf[2][72];            // padded
    __shared__ float4 pchunk[(16 * H_) / 4];  // 16-step pre1 chunk, 16 KB
    __shared__ float  wavesum[2][8];

    if (tid < 64) hbuf[0][tid + (tid >> 3)] = make_float4(0.f, 0.f, 0.f, 0.f);
    const int wloc = g + (g >> 3);

    int p = 0;
#pragma unroll 1
    for (int t0 = 0; t0 < T_; t0 += 16) {
        const float4* src = (const float4*)(pre1 + ((size_t)b * T_ + t0) * H_);
        pchunk[tid]       = src[tid];
        pchunk[tid + 512] = src[tid + 512];
        __syncthreads();
#pragma unroll 1
        for (int tt = 0; tt < 16; ++tt) {
            const int t = t0 + tt;
            if (tid == 0 && t > 0) {          // deferred FC store for step t-1
                float sfc = bfc;
#pragma unroll
                for (int wv = 0; wv < 8; ++wv) sfc += wavesum[p ^ 1][wv];
                out[(size_t)b * T_ + (t - 1)] = sfc;
            }
            float4 hv[8];
            const float4* hp = &hbuf[p][9 * s];
#pragma unroll
            for (int i = 0; i < 8; ++i) hv[i] = hp[i];
            float a[4] = {0.f, 0.f, 0.f, 0.f};
#pragma unroll
            for (int r = 0; r < 4; ++r)
#pragma unroll
                for (int i = 0; i < 8; ++i) {
                    a[r] = fmaf(hv[i].x, whh[r][i].x, a[r]);
                    a[r] = fmaf(hv[i].y, whh[r][i].y, a[r]);
                    a[r] = fmaf(hv[i].z, whh[r][i].z, a[r]);
                    a[r] = fmaf(hv[i].w, whh[r][i].w, a[r]);
                }
#pragma unroll
            for (int r = 0; r < 4; ++r) a[r] = red8(a[r]);
            const float4 pre = pchunk[tt * (H_ / 4) + g];
            float4 v;
            v.x = fmaxf(a[0] + pre.x, 0.f);
            v.y = fmaxf(a[1] + pre.y, 0.f);
            v.z = fmaxf(a[2] + pre.z, 0.f);
            v.w = fmaxf(a[3] + pre.w, 0.f);
            float fc = v.x * wfc4.x;
            fc = fmaf(v.y, wfc4.y, fc);
            fc = fmaf(v.z, wfc4.z, fc);
            fc = fmaf(v.w, wfc4.w, fc);
            fc += __shfl_xor(fc, 8, 64);      // sum over the wave's 8 quads
            fc += __shfl_xor(fc, 16, 64);
            fc += __shfl_xor(fc, 32, 64);
            if (s == 0) hbuf[p ^ 1][wloc] = v;
            if ((tid & 63) == 0) wavesum[p][tid >> 6] = fc;
            __syncthreads();
            p ^= 1;
        }
    }
    if (tid == 0) {                            // final step's FC store
        float sfc = bfc;
#pragma unroll
        for (int wv = 0; wv < 8; ++wv) sfc += wavesum[p ^ 1][wv];
        out[(size_t)b * T_ + (T_ - 1)] = sfc;
    }
}

extern "C" void kernel_launch(void* const* d_in, const int* in_sizes, int n_in,
                              void* d_out, int out_size, void* d_ws, size_t ws_size,
                              hipStream_t stream) {
    (void)in_sizes; (void)n_in; (void)out_size; (void)ws_size;
    const float* x    = (const float*)d_in[0];
    const float* Wih0 = (const float*)d_in[1];
    const float* Whh0 = (const float*)d_in[2];
    const float* bih0 = (const float*)d_in[3];
    const float* bhh0 = (const float*)d_in[4];
    const float* Wih1 = (const float*)d_in[5];
    const float* Whh1 = (const float*)d_in[6];
    const float* bih1 = (const float*)d_in[7];
    const float* bhh1 = (const float*)d_in[8];
    const float* Wfc  = (const float*)d_in[9];
    const float* bfc  = (const float*)d_in[10];

    float* buf = (float*)d_ws;      // B*T*H*4 = 128 MiB scratch
    float* out = (float*)d_out;

    k_layer0 <<<dim3(B_),             dim3(512), 0, stream>>>(x, Wih0, Whh0, bih0, bhh0, buf);
    k_inproj1<<<dim3((B_ * T_) / 64), dim3(512), 0, stream>>>(buf, Wih1, bih1, bhh1);
    k_layer1 <<<dim3(B_),             dim3(512), 0, stream>>>(buf, Whh1, Wfc, bfc, out);
}